// Round 9
// baseline (314.232 us; speedup 1.0000x reference)
//
#include <hip/hip_runtime.h>
#include <hip/hip_bf16.h>
#include <math.h>

#define B_ 4
#define N_ 1024
#define D_ 1024
#define H_ 16
#define HD_ 64
#define M_ (B_*N_)   // 4096

typedef __hip_bfloat16 bf16;
using floatx4 = __attribute__((ext_vector_type(4))) float;
using shortx8 = __attribute__((ext_vector_type(8))) short;

__device__ __forceinline__ float to_f(bf16 v) { return __bfloat162float(v); }
__device__ __forceinline__ float s2f(short v) {
    unsigned u = ((unsigned)(unsigned short)v) << 16;
    return __builtin_bit_cast(float, u);
}
__device__ __forceinline__ short bf_s(float x) {
    bf16 h = __float2bfloat16(x);
    return *reinterpret_cast<short*>(&h);
}

#define GLOBAL_AS __attribute__((address_space(1)))
#define LDS_AS    __attribute__((address_space(3)))
__device__ __forceinline__ void load_lds16(const void* g, void* l) {
    __builtin_amdgcn_global_load_lds((const GLOBAL_AS unsigned int*)g,
                                     (LDS_AS unsigned int*)l, 16, 0, 0);
}

__device__ __forceinline__ void storec(float* p, float v) { *p = v; }
__device__ __forceinline__ void storec(bf16*  p, float v) { *p = __float2bfloat16(v); }

// ---------------------------------------------------------------------------
// MFMA GEMM (round-7 structure): C = A @ W^T + bias (+resid).
// 128xBN block, 4 waves 2x2, BK=32, 16x16x32 bf16 MFMA, LDS dbuf with
// prefetch issued AFTER the frag ds_reads (measured best: 45.2 us FFN1).
// GROUP_M=8 block swizzle for W-panel L2 reuse.
// SPLIT: A cols [0,K1) from A, [K1,K) from A2.
// QKV: epilogue writes RoPE'd q,k [B,H,N,64] and transposed v [B,H,64,N]
//      directly (W rows pre-permuted to [q|k|v] head-major; pair via shfl).
// ---------------------------------------------------------------------------
template<typename TC, bool RESID, bool SPLIT, int BN, bool QKV>
__global__ __launch_bounds__(256)
void mgemm(const bf16* __restrict__ A, int lda,
           const bf16* __restrict__ A2, int lda2, int K1,
           const bf16* __restrict__ W, int ldw,
           const float* __restrict__ bias,
           const float* __restrict__ resid, int ldr,
           TC* __restrict__ C, int ldc,
           bf16* __restrict__ qd, bf16* __restrict__ kd, bf16* __restrict__ vtd,
           const float* __restrict__ enc,
           int M, int N, int K)
{
    constexpr int NT  = BN / 32;        // col 16-tiles per wave
    constexpr int ASZ = 128 * 32;
    constexpr int BSZ = BN * 32;
    __shared__ short lds[2 * (ASZ + BSZ)];

    int t = threadIdx.x;
    int lane = t & 63, quad = lane >> 4, l15 = lane & 15;
    int wave = t >> 6, wm = wave & 1, wn = wave >> 1;

    // GROUP_M=8 swizzle: 8 consecutive bids share one W-col panel
    int gx = gridDim.x;
    int bid = blockIdx.y * gx + blockIdx.x;
    int seg = bid / (8 * gx);
    int rem = bid - seg * 8 * gx;
    int bx = rem >> 3;
    int by = seg * 8 + (rem & 7);
    int row0 = by * 128, col0 = bx * BN;

    const short* Ag  = (const short*)A;
    const short* A2g = (const short*)A2;
    const short* Wg  = (const short*)W;

    auto stage = [&](int buf, int k0) {
        short* As = lds + buf * (ASZ + BSZ);
        short* Bs = As + ASZ;
        #pragma unroll
        for (int pass = 0; pass < 2; ++pass) {
            int idx = pass * 256 + t;
            int r = idx >> 2, c8 = (idx & 3) << 3;
            int wub = (pass * 256 + (t & 192)) * 8;    // wave-uniform LDS base
            const short* asrc;
            if (SPLIT && k0 >= K1)
                asrc = A2g + (size_t)(row0 + r) * lda2 + (k0 - K1) + c8;
            else
                asrc = Ag + (size_t)(row0 + r) * lda + k0 + c8;
            load_lds16(asrc, &As[wub]);
        }
        #pragma unroll
        for (int pass = 0; pass < BN / 64; ++pass) {
            int idx = pass * 256 + t;
            int r = idx >> 2, c8 = (idx & 3) << 3;
            int wub = (pass * 256 + (t & 192)) * 8;
            load_lds16(Wg + (size_t)(col0 + r) * ldw + k0 + c8, &Bs[wub]);
        }
    };

    floatx4 acc[4][NT];
    #pragma unroll
    for (int mt = 0; mt < 4; ++mt)
        #pragma unroll
        for (int nt = 0; nt < NT; ++nt)
            acc[mt][nt] = (floatx4){0.f, 0.f, 0.f, 0.f};

    stage(0, 0);
    int buf = 0;
    for (int k0 = 0; k0 < K; k0 += 32, buf ^= 1) {
        __syncthreads();   // drains this buf's staged loads; prev readers done
        const short* As = lds + buf * (ASZ + BSZ);
        const short* Bs = As + ASZ;
        shortx8 af[4], bfv[NT];
        #pragma unroll
        for (int mt = 0; mt < 4; ++mt)
            af[mt] = *(const shortx8*)&As[(wm * 64 + mt * 16 + l15) * 32 + quad * 8];
        #pragma unroll
        for (int nt = 0; nt < NT; ++nt)
            bfv[nt] = *(const shortx8*)&Bs[(wn * (BN / 2) + nt * 16 + l15) * 32 + quad * 8];
        if (k0 + 32 < K) stage(buf ^ 1, k0 + 32);   // prefetch flies over MFMAs
        #pragma unroll
        for (int mt = 0; mt < 4; ++mt)
            #pragma unroll
            for (int nt = 0; nt < NT; ++nt)
                acc[mt][nt] = __builtin_amdgcn_mfma_f32_16x16x32_bf16(
                    af[mt], bfv[nt], acc[mt][nt], 0, 0, 0);
    }

    if (QKV) {
        // cols are permuted-to [q(1024) | k(1024) | v(1024)], head-major h*64+d
        int sec = col0 >> 10;    // block-uniform (BN=128 divides 1024)
        #pragma unroll
        for (int mt = 0; mt < 4; ++mt) {
            #pragma unroll
            for (int nt = 0; nt < NT; ++nt) {
                int col = col0 + wn * (BN / 2) + nt * 16 + l15;
                int cl = col & 1023, h = cl >> 6, d = cl & 63;
                float bv = bias[col];
                float sgn = (d & 1) ? 1.0f : -1.0f;
                #pragma unroll
                for (int r = 0; r < 4; ++r) {
                    int row = row0 + wm * 64 + mt * 16 + quad * 4 + r;
                    int b = row >> 10, n = row & 1023;
                    float val = acc[mt][nt][r] + bv;
                    if (sec < 2) {
                        float pair = __shfl_xor(val, 1);   // col^1 = d^1 (lane^1)
                        size_t ei = ((size_t)(b * N_ + n)) * HD_ + d;
                        float cv = enc[ei];
                        float sv = enc[(size_t)B_ * N_ * HD_ + ei];
                        float ro = val * cv + sgn * pair * sv;
                        size_t o = (((size_t)(b * H_ + h)) * N_ + n) * HD_ + d;
                        if (sec == 0) qd[o] = __float2bfloat16(ro);
                        else          kd[o] = __float2bfloat16(ro);
                    } else {
                        vtd[(((size_t)(b * H_ + h)) * HD_ + d) * N_ + n] =
                            __float2bfloat16(val);
                    }
                }
            }
        }
        return;
    }

    #pragma unroll
    for (int mt = 0; mt < 4; ++mt) {
        #pragma unroll
        for (int nt = 0; nt < NT; ++nt) {
            int col = col0 + wn * (BN / 2) + nt * 16 + l15;
            float bv = bias[col];
            #pragma unroll
            for (int r = 0; r < 4; ++r) {
                int row = row0 + wm * 64 + mt * 16 + quad * 4 + r;
                float v = acc[mt][nt][r] + bv;
                if (RESID) v += resid[(size_t)row * ldr + col];
                storec(&C[(size_t)row * ldc + col], v);
            }
        }
    }
}

// fused fp32 -> bf16 convert: x, out_w, ffn1_w, ffn2_w plain; Wqkv row-permuted
// to [q|k|v] head-major (+ permuted fp32 bias).
__global__ void f2b_all(const float* __restrict__ s0, bf16* __restrict__ d0,
                        const float* __restrict__ s1, bf16* __restrict__ d1,
                        const float* __restrict__ s2, bf16* __restrict__ d2,
                        const float* __restrict__ s3, bf16* __restrict__ d3,
                        const float* __restrict__ wqkv, bf16* __restrict__ wq,
                        const float* __restrict__ bq, float* __restrict__ bqp)
{
    int blk = blockIdx.x;
    if (blk >= 11264) {   // Wqkv permuted rows
        int j = blk - 11264;                       // dst row in [0,3072)
        int sec = j >> 10, rr = j & 1023;
        int h = rr >> 6, d = rr & 63;
        int src = h * 192 + d * 3 + sec;
        const float* sp = wqkv + (size_t)src * 1024;
        bf16* dp = wq + (size_t)j * 1024;
        int i = threadIdx.x * 4;
        float4 v = *(const float4*)&sp[i];
        dp[i + 0] = __float2bfloat16(v.x);
        dp[i + 1] = __float2bfloat16(v.y);
        dp[i + 2] = __float2bfloat16(v.z);
        dp[i + 3] = __float2bfloat16(v.w);
        if (threadIdx.x == 0) bqp[j] = bq[src];
        return;
    }
    const float* s; bf16* d; int base;
    if      (blk < 4096)  { s = s0; d = d0; base = blk; }
    else if (blk < 5120)  { s = s1; d = d1; base = blk - 4096; }
    else if (blk < 9216)  { s = s2; d = d2; base = blk - 5120; }
    else                  { s = s3; d = d3; base = blk - 9216; }
    int i = base * 1024 + threadIdx.x * 4;
    float4 v = *(const float4*)&s[i];
    d[i + 0] = __float2bfloat16(v.x);
    d[i + 1] = __float2bfloat16(v.y);
    d[i + 2] = __float2bfloat16(v.z);
    d[i + 3] = __float2bfloat16(v.w);
}

// ---------------------------------------------------------------------------
// MFMA flash attention. Block = 128 q-rows of one (b,h); 4 waves x 32 rows.
// No max-tracking; row-sum per-lane, reduced in epilogue. V pre-transposed.
// ---------------------------------------------------------------------------
__global__ __launch_bounds__(256, 2)
void fattn(const bf16* __restrict__ q, const bf16* __restrict__ k,
           const bf16* __restrict__ vt, bf16* __restrict__ ctx)
{
    const int i0 = blockIdx.x * 128;
    const int h = blockIdx.y, b = blockIdx.z;
    const int t = threadIdx.x;
    const int lane = t & 63;
    const int w = t >> 6;
    const int quad = lane >> 4, l15 = lane & 15;

    __shared__ alignas(16) short Ks[64 * 72];
    __shared__ alignas(16) short Vs[64 * 72];
    __shared__ alignas(16) short Ps[128 * 72];

    const size_t bh = (size_t)(b * H_ + h) * N_;
    const size_t bhv = (size_t)(b * H_ + h) * HD_;
    const short* qg = (const short*)q;
    const short* kg = (const short*)k;
    const short* vg = (const short*)vt;

    shortx8 qf[2][2];
    #pragma unroll
    for (int rt = 0; rt < 2; ++rt) {
        const short* qrow = qg + (bh + i0 + w * 32 + rt * 16 + l15) * HD_;
        qf[rt][0] = *(const shortx8*)(qrow + quad * 8);
        qf[rt][1] = *(const shortx8*)(qrow + 32 + quad * 8);
    }

    floatx4 O[2][4];
    #pragma unroll
    for (int rt = 0; rt < 2; ++rt)
        #pragma unroll
        for (int dt = 0; dt < 4; ++dt) O[rt][dt] = (floatx4){0.f, 0.f, 0.f, 0.f};
    float lsum[2][4] = {};

    const int srow = t >> 2, soff = (t & 3) * 16;

    for (int j0 = 0; j0 < N_; j0 += 64) {
        __syncthreads();
        {
            const uint4* src = (const uint4*)(kg + (bh + j0 + srow) * HD_ + soff);
            uint4 a0 = src[0], a1 = src[1];
            *(uint4*)&Ks[srow * 72 + soff]     = a0;
            *(uint4*)&Ks[srow * 72 + soff + 8] = a1;
        }
        {
            const uint4* src = (const uint4*)(vg + (bhv + srow) * N_ + j0 + soff);
            uint4 a0 = src[0], a1 = src[1];
            *(uint4*)&Vs[srow * 72 + soff]     = a0;
            *(uint4*)&Vs[srow * 72 + soff + 8] = a1;
        }
        __syncthreads();

        floatx4 S[2][4];
        #pragma unroll
        for (int rt = 0; rt < 2; ++rt)
            #pragma unroll
            for (int ct = 0; ct < 4; ++ct) S[rt][ct] = (floatx4){0.f, 0.f, 0.f, 0.f};
        #pragma unroll
        for (int ct = 0; ct < 4; ++ct) {
            shortx8 b0 = *(const shortx8*)&Ks[(ct * 16 + l15) * 72 + quad * 8];
            shortx8 b1 = *(const shortx8*)&Ks[(ct * 16 + l15) * 72 + 32 + quad * 8];
            #pragma unroll
            for (int rt = 0; rt < 2; ++rt) {
                S[rt][ct] = __builtin_amdgcn_mfma_f32_16x16x32_bf16(qf[rt][0], b0, S[rt][ct], 0, 0, 0);
                S[rt][ct] = __builtin_amdgcn_mfma_f32_16x16x32_bf16(qf[rt][1], b1, S[rt][ct], 0, 0, 0);
            }
        }

        #pragma unroll
        for (int rt = 0; rt < 2; ++rt)
            #pragma unroll
            for (int ct = 0; ct < 4; ++ct)
                #pragma unroll
                for (int r = 0; r < 4; ++r) {
                    float e = __expf(S[rt][ct][r] * 0.125f);
                    lsum[rt][r] += e;
                    Ps[(w * 32 + rt * 16 + quad * 4 + r) * 72 + ct * 16 + l15] = bf_s(e);
                }

        shortx8 pa[2][2];
        #pragma unroll
        for (int rt = 0; rt < 2; ++rt) {
            pa[rt][0] = *(const shortx8*)&Ps[(w * 32 + rt * 16 + l15) * 72 + quad * 8];
            pa[rt][1] = *(const shortx8*)&Ps[(w * 32 + rt * 16 + l15) * 72 + 32 + quad * 8];
        }
        #pragma unroll
        for (int dt = 0; dt < 4; ++dt) {
            shortx8 vb0 = *(const shortx8*)&Vs[(dt * 16 + l15) * 72 + quad * 8];
            shortx8 vb1 = *(const shortx8*)&Vs[(dt * 16 + l15) * 72 + 32 + quad * 8];
            #pragma unroll
            for (int rt = 0; rt < 2; ++rt) {
                O[rt][dt] = __builtin_amdgcn_mfma_f32_16x16x32_bf16(pa[rt][0], vb0, O[rt][dt], 0, 0, 0);
                O[rt][dt] = __builtin_amdgcn_mfma_f32_16x16x32_bf16(pa[rt][1], vb1, O[rt][dt], 0, 0, 0);
            }
        }
    }

    #pragma unroll
    for (int rt = 0; rt < 2; ++rt)
        #pragma unroll
        for (int r = 0; r < 4; ++r) {
            float rs = lsum[rt][r];
            #pragma unroll
            for (int msk = 1; msk < 16; msk <<= 1)
                rs += __shfl_xor(rs, msk);
            float inv = 1.0f / rs;
            int row = i0 + w * 32 + rt * 16 + quad * 4 + r;
            #pragma unroll
            for (int dt = 0; dt < 4; ++dt)
                ctx[((size_t)(b * N_ + row)) * D_ + h * HD_ + dt * 16 + l15] =
                    __float2bfloat16(O[rt][dt][r] * inv);
        }
}

// LayerNorm over 2048 cols + exact GELU, in place on bf16. One block per row.
__global__ void ln_gelu(bf16* __restrict__ hbuf, const float* __restrict__ g,
                        const float* __restrict__ beta)
{
    int row = blockIdx.x;
    int t = threadIdx.x;
    bf16* hr = hbuf + (size_t)row * 2048;
    float vals[8];
    float s = 0.f, s2 = 0.f;
    #pragma unroll
    for (int l = 0; l < 8; ++l) {
        float x = to_f(hr[t + 256 * l]);
        vals[l] = x; s += x; s2 += x * x;
    }
    __shared__ float rs[256], rs2[256];
    rs[t] = s; rs2[t] = s2; __syncthreads();
    for (int k2 = 128; k2 > 0; k2 >>= 1) {
        if (t < k2) { rs[t] += rs[t + k2]; rs2[t] += rs2[t + k2]; }
        __syncthreads();
    }
    float mu  = rs[0] * (1.0f / 2048.0f);
    float var = rs2[0] * (1.0f / 2048.0f) - mu * mu;
    float rstd = rsqrtf(var + 1e-5f);
    #pragma unroll
    for (int l = 0; l < 8; ++l) {
        int c = t + 256 * l;
        float xn = (vals[l] - mu) * rstd * g[c] + beta[c];
        hr[c] = __float2bfloat16(0.5f * xn * (1.0f + erff(xn * 0.70710678118654752f)));
    }
}

extern "C" void kernel_launch(void* const* d_in, const int* in_sizes, int n_in,
                              void* d_out, int out_size, void* d_ws, size_t ws_size,
                              hipStream_t stream)
{
    const float* x      = (const float*)d_in[0];
    const float* enc    = (const float*)d_in[1];
    const float* Wqkv_w = (const float*)d_in[2];
    const float* Wqkv_b = (const float*)d_in[3];
    const float* out_w  = (const float*)d_in[4];
    const float* out_b  = (const float*)d_in[5];
    const float* ffn1_w = (const float*)d_in[6];
    const float* ffn1_b = (const float*)d_in[7];
    const float* ln_g   = (const float*)d_in[8];
    const float* ln_b   = (const float*)d_in[9];
    const float* ffn2_w = (const float*)d_in[10];
    const float* ffn2_b = (const float*)d_in[11];
    float* out = (float*)d_out;

    float* ws = (float*)d_ws;
    // regions (float offsets):
    // A [0, 6291456): ctx bf16 [0,2.1M) + h bf16 [2.1M,6.3M)
    // B [6291456, 12582912): q,k,vt bf16 (2.1M each); q overlaid by msg after fattn
    // C [12582912, 14680064): x16 bf16
    // D [14680064, 19922944): weights bf16; [19922944, 19926016): permuted qkv bias f32
    bf16* ctx16 = (bf16*)ws;
    bf16* h16   = (bf16*)(ws + 2097152);
    bf16* q16   = (bf16*)(ws + 6291456);
    bf16* k16   = q16 + 2097152;
    bf16* vt16  = k16 + 2097152;
    bf16* msg16 = (bf16*)(ws + 6291456);    // overlays q16 after fattn
    bf16* x16   = (bf16*)(ws + 12582912);
    bf16* wq16  = (bf16*)(ws + 14680064);
    bf16* wo16  = wq16 + 3145728;
    bf16* wf1   = wo16 + 1048576;
    bf16* wf2   = wf1 + 4194304;
    float* qkvb = ws + 19922944;            // permuted fp32 qkv bias [3072]

    // 0. fused converts: x, out_w, ffn1_w, ffn2_w plain; Wqkv permuted + bias
    f2b_all<<<14336, 256, 0, stream>>>(x, x16, out_w, wo16, ffn1_w, wf1,
                                       ffn2_w, wf2, Wqkv_w, wq16, Wqkv_b, qkvb);

    // 1. QKV GEMM with fused RoPE + V-transpose epilogue
    dim3 g1(3072 / 128, 4096 / 128);
    mgemm<bf16, false, false, 128, true><<<g1, 256, 0, stream>>>(
        x16, 1024, nullptr, 0, 0, wq16, 1024, qkvb, nullptr, 0,
        (bf16*)nullptr, 0, q16, k16, vt16, enc, 4096, 3072, 1024);

    // 2. MFMA flash attention -> ctx bf16 [4096, 1024]
    dim3 ga(N_ / 128, H_, B_);
    fattn<<<ga, 256, 0, stream>>>(q16, k16, vt16, ctx16);

    // 3. message = ctx @ out_w^T + out_b -> msg16 (BN=64: 512 blocks)
    dim3 g2(1024 / 64, 4096 / 128);
    mgemm<bf16, false, false, 64, false><<<g2, 256, 0, stream>>>(
        ctx16, 1024, nullptr, 0, 0, wo16, 1024, out_b, nullptr, 0,
        msg16, 1024, nullptr, nullptr, nullptr, nullptr, 4096, 1024, 1024);

    // 4. h = [x | message] @ ffn1_w^T + ffn1_b  [4096, 2048] (split-A)
    dim3 g3(2048 / 128, 4096 / 128);
    mgemm<bf16, false, true, 128, false><<<g3, 256, 0, stream>>>(
        x16, 1024, msg16, 1024, 1024, wf1, 2048, ffn1_b, nullptr, 0,
        h16, 2048, nullptr, nullptr, nullptr, nullptr, 4096, 2048, 2048);

    // 5. LayerNorm + exact GELU in place (bf16)
    ln_gelu<<<4096, 256, 0, stream>>>(h16, ln_g, ln_b);

    // 6. out = x + h @ ffn2_w^T + ffn2_b  [4096, 1024] fp32 (BN=64)
    dim3 g4(1024 / 64, 4096 / 128);
    mgemm<float, true, false, 64, false><<<g4, 256, 0, stream>>>(
        h16, 2048, nullptr, 0, 0, wf2, 2048, ffn2_b, x, 1024,
        out, 1024, nullptr, nullptr, nullptr, nullptr, 4096, 1024, 2048);
}

// Round 10
// 296.279 us; speedup vs baseline: 1.0606x; 1.0606x over previous
//
#include <hip/hip_runtime.h>
#include <hip/hip_bf16.h>
#include <math.h>

#define B_ 4
#define N_ 1024
#define D_ 1024
#define H_ 16
#define HD_ 64
#define M_ (B_*N_)   // 4096

typedef __hip_bfloat16 bf16;
using floatx4 = __attribute__((ext_vector_type(4))) float;
using shortx8 = __attribute__((ext_vector_type(8))) short;

__device__ __forceinline__ float to_f(bf16 v) { return __bfloat162float(v); }
__device__ __forceinline__ float s2f(short v) {
    unsigned u = ((unsigned)(unsigned short)v) << 16;
    return __builtin_bit_cast(float, u);
}
__device__ __forceinline__ unsigned short bf_bits(float x) {
    bf16 h = __float2bfloat16(x);
    return *reinterpret_cast<unsigned short*>(&h);
}

#define GLOBAL_AS __attribute__((address_space(1)))
#define LDS_AS    __attribute__((address_space(3)))
__device__ __forceinline__ void load_lds16(const void* g, void* l) {
    __builtin_amdgcn_global_load_lds((const GLOBAL_AS unsigned int*)g,
                                     (LDS_AS unsigned int*)l, 16, 0, 0);
}

__device__ __forceinline__ void storec(float* p, float v) { *p = v; }
__device__ __forceinline__ void storec(bf16*  p, float v) { *p = __float2bfloat16(v); }

// ---------------------------------------------------------------------------
// MFMA GEMM (round-7 measured-best): C = A @ W^T + bias (+resid).
// 128xBN block, 4 waves 2x2, BK=32, 16x16x32 bf16 MFMA, LDS dbuf with
// prefetch issued AFTER the frag ds_reads. GROUP_M=8 swizzle for L2 reuse.
// SPLIT: A cols [0,K1) from A, [K1,K) from A2.
// ---------------------------------------------------------------------------
template<typename TC, bool RESID, bool SPLIT, int BN>
__global__ __launch_bounds__(256)
void mgemm(const bf16* __restrict__ A, int lda,
           const bf16* __restrict__ A2, int lda2, int K1,
           const bf16* __restrict__ W, int ldw,
           const float* __restrict__ bias,
           const float* __restrict__ resid, int ldr,
           TC* __restrict__ C, int ldc,
           int M, int N, int K)
{
    constexpr int NT  = BN / 32;        // col 16-tiles per wave
    constexpr int ASZ = 128 * 32;
    constexpr int BSZ = BN * 32;
    __shared__ short lds[2 * (ASZ + BSZ)];

    int t = threadIdx.x;
    int lane = t & 63, quad = lane >> 4, l15 = lane & 15;
    int wave = t >> 6, wm = wave & 1, wn = wave >> 1;

    // GROUP_M=8 swizzle: 8 consecutive bids share one W-col panel
    int gx = gridDim.x;
    int bid = blockIdx.y * gx + blockIdx.x;
    int seg = bid / (8 * gx);
    int rem = bid - seg * 8 * gx;
    int bx = rem >> 3;
    int by = seg * 8 + (rem & 7);
    int row0 = by * 128, col0 = bx * BN;

    const short* Ag  = (const short*)A;
    const short* A2g = (const short*)A2;
    const short* Wg  = (const short*)W;

    auto stage = [&](int buf, int k0) {
        short* As = lds + buf * (ASZ + BSZ);
        short* Bs = As + ASZ;
        #pragma unroll
        for (int pass = 0; pass < 2; ++pass) {
            int idx = pass * 256 + t;
            int r = idx >> 2, c8 = (idx & 3) << 3;
            int wub = (pass * 256 + (t & 192)) * 8;    // wave-uniform LDS base
            const short* asrc;
            if (SPLIT && k0 >= K1)
                asrc = A2g + (size_t)(row0 + r) * lda2 + (k0 - K1) + c8;
            else
                asrc = Ag + (size_t)(row0 + r) * lda + k0 + c8;
            load_lds16(asrc, &As[wub]);
        }
        #pragma unroll
        for (int pass = 0; pass < BN / 64; ++pass) {
            int idx = pass * 256 + t;
            int r = idx >> 2, c8 = (idx & 3) << 3;
            int wub = (pass * 256 + (t & 192)) * 8;
            load_lds16(Wg + (size_t)(col0 + r) * ldw + k0 + c8, &Bs[wub]);
        }
    };

    floatx4 acc[4][NT];
    #pragma unroll
    for (int mt = 0; mt < 4; ++mt)
        #pragma unroll
        for (int nt = 0; nt < NT; ++nt)
            acc[mt][nt] = (floatx4){0.f, 0.f, 0.f, 0.f};

    stage(0, 0);
    int buf = 0;
    for (int k0 = 0; k0 < K; k0 += 32, buf ^= 1) {
        __syncthreads();   // drains this buf's staged loads; prev readers done
        const short* As = lds + buf * (ASZ + BSZ);
        const short* Bs = As + ASZ;
        shortx8 af[4], bfv[NT];
        #pragma unroll
        for (int mt = 0; mt < 4; ++mt)
            af[mt] = *(const shortx8*)&As[(wm * 64 + mt * 16 + l15) * 32 + quad * 8];
        #pragma unroll
        for (int nt = 0; nt < NT; ++nt)
            bfv[nt] = *(const shortx8*)&Bs[(wn * (BN / 2) + nt * 16 + l15) * 32 + quad * 8];
        if (k0 + 32 < K) stage(buf ^ 1, k0 + 32);   // prefetch flies over MFMAs
        #pragma unroll
        for (int mt = 0; mt < 4; ++mt)
            #pragma unroll
            for (int nt = 0; nt < NT; ++nt)
                acc[mt][nt] = __builtin_amdgcn_mfma_f32_16x16x32_bf16(
                    af[mt], bfv[nt], acc[mt][nt], 0, 0, 0);
    }

    #pragma unroll
    for (int mt = 0; mt < 4; ++mt) {
        #pragma unroll
        for (int nt = 0; nt < NT; ++nt) {
            int col = col0 + wn * (BN / 2) + nt * 16 + l15;
            float bv = bias[col];
            #pragma unroll
            for (int r = 0; r < 4; ++r) {
                int row = row0 + wm * 64 + mt * 16 + quad * 4 + r;
                float v = acc[mt][nt][r] + bv;
                if (RESID) v += resid[(size_t)row * ldr + col];
                storec(&C[(size_t)row * ldc + col], v);
            }
        }
    }
}

// fused fp32 -> bf16 convert for 5 tensors; each block handles 1024 elems
__global__ void f2b_all(const float* __restrict__ s0, bf16* __restrict__ d0,
                        const float* __restrict__ s1, bf16* __restrict__ d1,
                        const float* __restrict__ s2, bf16* __restrict__ d2,
                        const float* __restrict__ s3, bf16* __restrict__ d3,
                        const float* __restrict__ s4, bf16* __restrict__ d4)
{
    int blk = blockIdx.x;
    const float* s; bf16* d; int base;
    if      (blk < 4096)  { s = s0; d = d0; base = blk; }
    else if (blk < 7168)  { s = s1; d = d1; base = blk - 4096; }
    else if (blk < 8192)  { s = s2; d = d2; base = blk - 7168; }
    else if (blk < 12288) { s = s3; d = d3; base = blk - 8192; }
    else                  { s = s4; d = d4; base = blk - 12288; }
    int i = base * 1024 + threadIdx.x * 4;
    float4 v = *(const float4*)&s[i];
    d[i + 0] = __float2bfloat16(v.x);
    d[i + 1] = __float2bfloat16(v.y);
    d[i + 2] = __float2bfloat16(v.z);
    d[i + 3] = __float2bfloat16(v.w);
}

// ---------------------------------------------------------------------------
// rope_all: block = (n-tile 64, h, b). Reads qkv[b,n][h*192 + d*3 + c] once via
// an LDS tile, writes RoPE'd q,k in [B,H,N,64] and V transposed in [B,H,64,N].
// ---------------------------------------------------------------------------
#define RS 196
__global__ __launch_bounds__(256)
void rope_all(const bf16* __restrict__ qkv, const float* __restrict__ enc,
              bf16* __restrict__ q, bf16* __restrict__ k, bf16* __restrict__ vt)
{
    __shared__ short raw[64 * RS];
    int n0 = blockIdx.x * 64, h = blockIdx.y, b = blockIdx.z;
    int t = threadIdx.x;
    const short* qg = (const short*)qkv;

    {
        int row = t >> 2, off = (t & 3) * 48;
        const short* src = qg + ((size_t)(b * N_ + n0 + row)) * 3072 + h * 192 + off;
        uint4 u[3];
        u[0] = ((const uint4*)src)[0];
        u[1] = ((const uint4*)src)[1];
        u[2] = ((const uint4*)src)[2];
        uint4 u2[3];
        u2[0] = ((const uint4*)src)[3];
        u2[1] = ((const uint4*)src)[4];
        u2[2] = ((const uint4*)src)[5];
        uint2* dst = (uint2*)&raw[row * RS + off];
        const uint2* p = (const uint2*)u;
        #pragma unroll
        for (int i = 0; i < 6; ++i) dst[i] = p[i];
        const uint2* p2 = (const uint2*)u2;
        #pragma unroll
        for (int i = 0; i < 6; ++i) dst[6 + i] = p2[i];
    }
    __syncthreads();

    size_t bh = (size_t)(b * H_ + h);
    {
        int d = t & 63, g0 = t >> 6;
        int dp = d ^ 1;
        float sgn = (d & 1) ? 1.0f : -1.0f;
        #pragma unroll
        for (int i = 0; i < 16; ++i) {
            int nl = g0 + 4 * i;
            const short* r = &raw[nl * RS];
            float qv = s2f(r[3 * d]),  kv = s2f(r[3 * d + 1]);
            float qp = s2f(r[3 * dp]), kp = s2f(r[3 * dp + 1]);
            size_t ei = ((size_t)(b * N_ + n0 + nl)) * HD_ + d;
            float c = enc[ei];
            float s = enc[(size_t)B_ * N_ * HD_ + ei];
            size_t o = (bh * N_ + n0 + nl) * HD_ + d;
            q[o] = __float2bfloat16(qv * c + sgn * qp * s);
            k[o] = __float2bfloat16(kv * c + sgn * kp * s);
        }
    }
    {
        int nl = t & 63, g0 = t >> 6;
        #pragma unroll
        for (int i = 0; i < 16; ++i) {
            int dt = g0 + 4 * i;
            vt[(bh * HD_ + dt) * N_ + n0 + nl] =
                *reinterpret_cast<bf16*>(&raw[nl * RS + 3 * dt + 2]);
        }
    }
}

// ---------------------------------------------------------------------------
// MFMA flash attention v4. Block = 128 q-rows of one (b,h); 4 waves x 32 rows.
// S computed TRANSPOSED (S^T = K Q^T): each lane then holds 4 CONSECUTIVE keys
// of one q-row -> P staged with 8 ds_write_b64 per iter (was 32 ds_write_b16).
// No max-tracking; per-lane key-subset row sums, redistributed via shfl in
// the epilogue. V pre-transposed in global ([B,H,64,N]).
// ---------------------------------------------------------------------------
__global__ __launch_bounds__(256, 2)
void fattn(const bf16* __restrict__ q, const bf16* __restrict__ k,
           const bf16* __restrict__ vt, bf16* __restrict__ ctx)
{
    const int i0 = blockIdx.x * 128;
    const int h = blockIdx.y, b = blockIdx.z;
    const int t = threadIdx.x;
    const int lane = t & 63;
    const int w = t >> 6;
    const int quad = lane >> 4, l15 = lane & 15;

    __shared__ alignas(16) short Ks[64 * 72];    // [key][d]
    __shared__ alignas(16) short Vs[64 * 72];    // [d][key]
    __shared__ alignas(16) short Ps[128 * 72];   // [q-row][key]

    const size_t bh = (size_t)(b * H_ + h) * N_;
    const size_t bhv = (size_t)(b * H_ + h) * HD_;
    const short* qg = (const short*)q;
    const short* kg = (const short*)k;
    const short* vg = (const short*)vt;

    // Q fragments (B-operand: n = q-row = l15, k = quad*8+j)
    shortx8 qf[2][2];
    #pragma unroll
    for (int rt = 0; rt < 2; ++rt) {
        const short* qrow = qg + (bh + i0 + w * 32 + rt * 16 + l15) * HD_;
        qf[rt][0] = *(const shortx8*)(qrow + quad * 8);
        qf[rt][1] = *(const shortx8*)(qrow + 32 + quad * 8);
    }

    floatx4 O[2][4];
    #pragma unroll
    for (int rt = 0; rt < 2; ++rt)
        #pragma unroll
        for (int dt = 0; dt < 4; ++dt) O[rt][dt] = (floatx4){0.f, 0.f, 0.f, 0.f};
    // per-lane partial row sums: q-row = w*32 + rt*16 + l15, keys {16kt + quad*4 + r}
    float lsum[2] = {0.f, 0.f};

    const int srow = t >> 2, soff = (t & 3) * 16;

    for (int j0 = 0; j0 < N_; j0 += 64) {
        __syncthreads();
        {   // stage K tile [key][d]
            const uint4* src = (const uint4*)(kg + (bh + j0 + srow) * HD_ + soff);
            uint4 a0 = src[0], a1 = src[1];
            *(uint4*)&Ks[srow * 72 + soff]     = a0;
            *(uint4*)&Ks[srow * 72 + soff + 8] = a1;
        }
        {   // stage V^T tile [d][key]
            const uint4* src = (const uint4*)(vg + (bhv + srow) * N_ + j0 + soff);
            uint4 a0 = src[0], a1 = src[1];
            *(uint4*)&Vs[srow * 72 + soff]     = a0;
            *(uint4*)&Vs[srow * 72 + soff + 8] = a1;
        }
        __syncthreads();

        // S^T = K Q^T : A = K-frag (m=key), B = Q-frag (n=q-row)
        // C-layout: col(l15) = q-row, row(quad*4+r) = key
        floatx4 ST[4][2];
        #pragma unroll
        for (int kt = 0; kt < 4; ++kt) {
            shortx8 a0 = *(const shortx8*)&Ks[(kt * 16 + l15) * 72 + quad * 8];
            shortx8 a1 = *(const shortx8*)&Ks[(kt * 16 + l15) * 72 + 32 + quad * 8];
            #pragma unroll
            for (int rt = 0; rt < 2; ++rt) {
                floatx4 c = (floatx4){0.f, 0.f, 0.f, 0.f};
                c = __builtin_amdgcn_mfma_f32_16x16x32_bf16(a0, qf[rt][0], c, 0, 0, 0);
                c = __builtin_amdgcn_mfma_f32_16x16x32_bf16(a1, qf[rt][1], c, 0, 0, 0);
                ST[kt][rt] = c;
            }
        }

        // exp + per-lane sums + packed b64 P-writes (4 consecutive keys/lane)
        #pragma unroll
        for (int kt = 0; kt < 4; ++kt)
            #pragma unroll
            for (int rt = 0; rt < 2; ++rt) {
                unsigned short pk[4];
                #pragma unroll
                for (int r = 0; r < 4; ++r) {
                    float e = __expf(ST[kt][rt][r] * 0.125f);
                    lsum[rt] += e;
                    pk[r] = bf_bits(e);
                }
                *(uint2*)&Ps[(w * 32 + rt * 16 + l15) * 72 + kt * 16 + quad * 4] =
                    *(const uint2*)pk;
            }

        // PV (same-wave Ps write->read; per-wave LDS ordering)
        shortx8 pa[2][2];
        #pragma unroll
        for (int rt = 0; rt < 2; ++rt) {
            pa[rt][0] = *(const shortx8*)&Ps[(w * 32 + rt * 16 + l15) * 72 + quad * 8];
            pa[rt][1] = *(const shortx8*)&Ps[(w * 32 + rt * 16 + l15) * 72 + 32 + quad * 8];
        }
        #pragma unroll
        for (int dt = 0; dt < 4; ++dt) {
            shortx8 vb0 = *(const shortx8*)&Vs[(dt * 16 + l15) * 72 + quad * 8];
            shortx8 vb1 = *(const shortx8*)&Vs[(dt * 16 + l15) * 72 + 32 + quad * 8];
            #pragma unroll
            for (int rt = 0; rt < 2; ++rt) {
                O[rt][dt] = __builtin_amdgcn_mfma_f32_16x16x32_bf16(pa[rt][0], vb0, O[rt][dt], 0, 0, 0);
                O[rt][dt] = __builtin_amdgcn_mfma_f32_16x16x32_bf16(pa[rt][1], vb1, O[rt][dt], 0, 0, 0);
            }
        }
    }

    // epilogue: complete row sums (reduce across quads -> full sum at q-row=l15),
    // redistribute to O's row indexing (q-row = quad*4 + r) via shfl, store.
    #pragma unroll
    for (int rt = 0; rt < 2; ++rt) {
        float rs = lsum[rt];
        rs += __shfl_xor(rs, 16);
        rs += __shfl_xor(rs, 32);
        #pragma unroll
        for (int r = 0; r < 4; ++r) {
            float inv = 1.0f / __shfl(rs, quad * 4 + r);
            int row = i0 + w * 32 + rt * 16 + quad * 4 + r;
            #pragma unroll
            for (int dt = 0; dt < 4; ++dt)
                ctx[((size_t)(b * N_ + row)) * D_ + h * HD_ + dt * 16 + l15] =
                    __float2bfloat16(O[rt][dt][r] * inv);
        }
    }
}

// LayerNorm over 2048 cols + exact GELU, in place on bf16. One block per row.
__global__ void ln_gelu(bf16* __restrict__ hbuf, const float* __restrict__ g,
                        const float* __restrict__ beta)
{
    int row = blockIdx.x;
    int t = threadIdx.x;
    bf16* hr = hbuf + (size_t)row * 2048;
    float vals[8];
    float s = 0.f, s2 = 0.f;
    #pragma unroll
    for (int l = 0; l < 8; ++l) {
        float x = to_f(hr[t + 256 * l]);
        vals[l] = x; s += x; s2 += x * x;
    }
    __shared__ float rs[256], rs2[256];
    rs[t] = s; rs2[t] = s2; __syncthreads();
    for (int k2 = 128; k2 > 0; k2 >>= 1) {
        if (t < k2) { rs[t] += rs[t + k2]; rs2[t] += rs2[t + k2]; }
        __syncthreads();
    }
    float mu  = rs[0] * (1.0f / 2048.0f);
    float var = rs2[0] * (1.0f / 2048.0f) - mu * mu;
    float rstd = rsqrtf(var + 1e-5f);
    #pragma unroll
    for (int l = 0; l < 8; ++l) {
        int c = t + 256 * l;
        float xn = (vals[l] - mu) * rstd * g[c] + beta[c];
        hr[c] = __float2bfloat16(0.5f * xn * (1.0f + erff(xn * 0.70710678118654752f)));
    }
}

extern "C" void kernel_launch(void* const* d_in, const int* in_sizes, int n_in,
                              void* d_out, int out_size, void* d_ws, size_t ws_size,
                              hipStream_t stream)
{
    const float* x      = (const float*)d_in[0];
    const float* enc    = (const float*)d_in[1];
    const float* Wqkv_w = (const float*)d_in[2];
    const float* Wqkv_b = (const float*)d_in[3];
    const float* out_w  = (const float*)d_in[4];
    const float* out_b  = (const float*)d_in[5];
    const float* ffn1_w = (const float*)d_in[6];
    const float* ffn1_b = (const float*)d_in[7];
    const float* ln_g   = (const float*)d_in[8];
    const float* ln_b   = (const float*)d_in[9];
    const float* ffn2_w = (const float*)d_in[10];
    const float* ffn2_b = (const float*)d_in[11];
    float* out = (float*)d_out;

    float* ws = (float*)d_ws;
    // regions (float offsets):
    // A [0, 6291456): qkv bf16 [4096,3072] -> after rope_all: ctx [0,2.1M) + h [2.1M,6.3M)
    // B [6291456, 12582912): q,k,vt bf16 (2.1M each); q overlaid by msg after fattn
    // C [12582912, 14680064): x16 bf16
    // D [14680064, 19922944): weights bf16
    bf16* qkv16 = (bf16*)ws;
    bf16* ctx16 = (bf16*)ws;
    bf16* h16   = (bf16*)(ws + 2097152);
    bf16* q16   = (bf16*)(ws + 6291456);
    bf16* k16   = q16 + 2097152;
    bf16* vt16  = k16 + 2097152;
    bf16* msg16 = (bf16*)(ws + 6291456);    // overlays q16 after fattn
    bf16* x16   = (bf16*)(ws + 12582912);
    bf16* wq16  = (bf16*)(ws + 14680064);
    bf16* wo16  = wq16 + 3145728;
    bf16* wf1   = wo16 + 1048576;
    bf16* wf2   = wf1 + 4194304;

    // 0. fused converts (x, Wqkv, out_w, ffn1_w, ffn2_w)
    f2b_all<<<14336, 256, 0, stream>>>(x, x16, Wqkv_w, wq16, out_w, wo16,
                                       ffn1_w, wf1, ffn2_w, wf2);

    // 1. qkv = x @ Wqkv^T + b   [4096, 3072] bf16
    dim3 g1(3072 / 128, 4096 / 128);
    mgemm<bf16, false, false, 128><<<g1, 256, 0, stream>>>(
        x16, 1024, nullptr, 0, 0, wq16, 1024, Wqkv_b, nullptr, 0,
        qkv16, 3072, 4096, 3072, 1024);

    // 2. RoPE + split + V-transpose
    dim3 gr(16, 16, 4);
    rope_all<<<gr, 256, 0, stream>>>(qkv16, enc, q16, k16, vt16);

    // 3. MFMA flash attention -> ctx bf16 [4096, 1024]
    dim3 ga(N_ / 128, H_, B_);
    fattn<<<ga, 256, 0, stream>>>(q16, k16, vt16, ctx16);

    // 4. message = ctx @ out_w^T + out_b -> msg16 (BN=64: 512 blocks)
    dim3 g2(1024 / 64, 4096 / 128);
    mgemm<bf16, false, false, 64><<<g2, 256, 0, stream>>>(
        ctx16, 1024, nullptr, 0, 0, wo16, 1024, out_b, nullptr, 0,
        msg16, 1024, 4096, 1024, 1024);

    // 5. h = [x | message] @ ffn1_w^T + ffn1_b  [4096, 2048] (split-A)
    dim3 g3(2048 / 128, 4096 / 128);
    mgemm<bf16, false, true, 128><<<g3, 256, 0, stream>>>(
        x16, 1024, msg16, 1024, 1024, wf1, 2048, ffn1_b, nullptr, 0,
        h16, 2048, 4096, 2048, 2048);

    // 6. LayerNorm + exact GELU in place (bf16)
    ln_gelu<<<4096, 256, 0, stream>>>(h16, ln_g, ln_b);

    // 7. out = x + h @ ffn2_w^T + ffn2_b  [4096, 1024] fp32 (BN=64)
    dim3 g4(1024 / 64, 4096 / 128);
    mgemm<float, true, false, 64><<<g4, 256, 0, stream>>>(
        h16, 2048, nullptr, 0, 0, wf2, 2048, ffn2_b, x, 1024,
        out, 1024, 4096, 1024, 2048);
}